// Round 4
// baseline (2467.771 us; speedup 1.0000x reference)
//
#include <hip/hip_runtime.h>

#define HDIM 2048
#define TSTEPS 1024
#define NBLK 256
#define NTHR 512
#define CPB 8
#define TAGM 0x3FFu
#define NREP 16
#define RSTRIDE 2112u   // u32 per replica = 8KB + 256B (channel decorrelation)

typedef unsigned long long ull;

__device__ __forceinline__ int snake_src(int t) {
    int y = t >> 5, p = t & 31;
    return (y & 1) ? (y * 32 + 31 - p) : t;
}
__device__ __forceinline__ float sigmoid_f(float v) {
    return __builtin_amdgcn_rcpf(1.f + __expf(-v));
}
__device__ __forceinline__ float tanh_f(float v) {
    return 1.f - 2.f * __builtin_amdgcn_rcpf(__expf(2.f * v) + 1.f);
}
// broadcast from lane ((lane & 0x18) | G) within the 32-lane half; our
// 8-lane groups (bits 3,4 + half bit 5) are closed under this swizzle.
template<int G>
__device__ __forceinline__ float bcast8(float v) {
    return __uint_as_float((unsigned)__builtin_amdgcn_ds_swizzle(
        (int)__float_as_uint(v), (G << 5) | 0x18));
}

// ---------------------------------------------------------------------------
// R4 = R3 protocol (coalesced wave0 tagged publish, replicated slots, sleep
// backoff, tag-in-mantissa parity buffers u0/u1) with the in-block
// distribution round-trip deleted:
//   1. KEY: thread tid polls rows 4t..4t+3 == exactly what its 8-lane group
//      (tid&~7) needs for its 32-row dot product. ds_swizzle intra-group
//      broadcast replaces {LDS stage + BAR1 + 32 ds_reads}. 2 barriers/step.
//   2. finalize via ds_add_f32: lanes<8 of each wave atomicAdd their wave
//      partials into sAcc[3][8]; cells pre-initialized with next step's
//      input terms (aR,aZ) and bhn during the PREVIOUS finalize (BAR3
//      separates init from next step's adds). Wave0 finalize = 3 LDS reads
//      + gates (was 24 serial reads + sum).
//   3. hold: threads with tid>>1==blk (they poll this block's own 8 cols)
//      write them to sHold[8] pre-BAR2.
//   4. NREP=16 via one dwordx2 store per wave0 lane (lane -> replica
//      lane>>2, col pair 2*(lane&3)); consumers poll replica blk&15.
//   5. __launch_bounds__(512,1): we run 1 block/CU; the old ,2 capped the
//      allocator at 128 VGPR and likely forced the 96 weights through
//      AGPR moves.
// Publish packs tag round-to-nearest: rel err <= 2^-14/hop. Poison 0xAA..:
// low10=682; every slot is rewritten every 2 steps — no false match.
// ---------------------------------------------------------------------------
__global__ __launch_bounds__(NTHR, 1) void gru_all(
    const float* __restrict__ x,
    const float* __restrict__ We,  const float* __restrict__ be,
    const float* __restrict__ Wir, const float* __restrict__ bir,
    const float* __restrict__ Wiz, const float* __restrict__ biz,
    const float* __restrict__ Win, const float* __restrict__ bin_,
    const float* __restrict__ Whr, const float* __restrict__ Whz,
    const float* __restrict__ Whn, const float* __restrict__ bhn,
    float* __restrict__ out, unsigned* __restrict__ u0, unsigned* __restrict__ u1)
{
    const int tid  = threadIdx.x;
    const int blk  = blockIdx.x;
    const int c    = tid & 7;
    const int r    = tid >> 3;            // 0..63
    const int col  = blk * CPB + c;
    const int row0 = r * 32;
    const int lane = tid & 63, wv = tid >> 6;

    __shared__ float red[8][6][8];        // init-phase cross-wave reduce
    __shared__ float sX[TSTEPS];          // x in snake order
    __shared__ float sAcc[3][8];          // per-step gate accumulators
    __shared__ float sHold[8];            // h_t for this block's 8 cols

    // ---- one-time: x (snake order) into LDS ----
    for (int i = tid; i < TSTEPS; i += NTHR) sX[i] = x[snake_src(i)];

    // ---- recurrent weights into registers (one-time) ----
    float wr[32], wz[32], wn[32];
#pragma unroll
    for (int k = 0; k < 32; ++k) {
        size_t off = (size_t)(row0 + k) * HDIM + col;
        wr[k] = Whr[off];
        wz[k] = Whz[off];
        wn[k] = Whn[off];
    }

    // ---- rank-1 input-path constants (We/be direct from global) ----
    float eR=0,eZ=0,eN=0,bRa=0,bZa=0,bNa=0;
#pragma unroll 8
    for (int k = 0; k < 32; ++k) {
        int row = row0 + k;
        size_t off = (size_t)row * HDIM + col;
        float we = We[row], bb = be[row];
        float w0 = Wir[off], w1 = Wiz[off], w2 = Win[off];
        eR  = fmaf(we, w0, eR);  bRa = fmaf(bb, w0, bRa);
        eZ  = fmaf(we, w1, eZ);  bZa = fmaf(bb, w1, bZa);
        eN  = fmaf(we, w2, eN);  bNa = fmaf(bb, w2, bNa);
    }
#pragma unroll
    for (int m = 8; m < 64; m <<= 1) {
        eR  += __shfl_xor(eR,  m, 64); eZ  += __shfl_xor(eZ,  m, 64);
        eN  += __shfl_xor(eN,  m, 64); bRa += __shfl_xor(bRa, m, 64);
        bZa += __shfl_xor(bZa, m, 64); bNa += __shfl_xor(bNa, m, 64);
    }
    if (lane < 8) {
        red[wv][0][lane]=eR;  red[wv][1][lane]=eZ;  red[wv][2][lane]=eN;
        red[wv][3][lane]=bRa; red[wv][4][lane]=bZa; red[wv][5][lane]=bNa;
    }
    __syncthreads();   // red + sX staged

    float vrc=0,vzc=0,vnc=0,crc=0,czc=0,cnc=0,bhc=0;
    float aN=0;
    unsigned pk1 = 0;
    if (tid < 8) {
#pragma unroll
        for (int w = 0; w < 8; ++w) {
            vrc += red[w][0][tid]; vzc += red[w][1][tid]; vnc += red[w][2][tid];
            crc += red[w][3][tid]; czc += red[w][4][tid]; cnc += red[w][5][tid];
        }
        crc += bir[col]; czc += biz[col]; cnc += bin_[col];
        bhc = bhn[col];

        // ---- step 0: h_0 == 0, fully local; h_1 with tag 1 ----
        float x0 = sX[0];
        float ar = fmaf(x0, vrc, crc);
        float az = fmaf(x0, vzc, czc);
        float an = fmaf(x0, vnc, cnc);
        float rg = sigmoid_f(ar), zg = sigmoid_f(az);
        float ng = tanh_f(fmaf(rg, bhc, an));
        float h1 = (1.f - zg) * ng;
        pk1 = ((__float_as_uint(h1) + 512u) & ~TAGM) | 1u;

        // precompute t=1 input terms; initialize the t=1 accumulator cells
        float x1 = sX[1];
        sAcc[0][tid] = fmaf(x1, vrc, crc);
        sAcc[1][tid] = fmaf(x1, vzc, czc);
        aN           = fmaf(x1, vnc, cnc);
        sAcc[2][tid] = bhc;
    }
    // replicated step-0 publish: one dwordx2 store per wave0 lane
    if (wv == 0) {
        unsigned c0  = (lane & 3) * 2;
        unsigned pkA = __shfl(pk1, (int)c0,     64);
        unsigned pkB = __shfl(pk1, (int)c0 + 1, 64);
        ull pkk = (ull)pkA | ((ull)pkB << 32);
        ull* dst = (ull*)u1 + (ull)(lane >> 2) * (RSTRIDE / 2)
                 + (ull)blk * 4 + (ull)(lane & 3);
        __hip_atomic_store(dst, pkk, __ATOMIC_RELAXED, __HIP_MEMORY_SCOPE_AGENT);
    }
    __syncthreads();   // sAcc init + publish issued before anyone polls t=1

    const ull  M2     = 0x000003FF000003FFull;
    const ull  repoff = (ull)(blk & 15) * (RSTRIDE / 2);   // ull units

    for (int t = 1; t < TSTEPS; ++t) {
        const unsigned* pin  = (t & 1) ? u1 : u0;
        unsigned*       pout = (t & 1) ? u0 : u1;
        const unsigned  tg   = (unsigned)t & TAGM;
        const ull       tg2  = ((ull)tg << 32) | (ull)tg;

        // ---- poll assigned replica: 2x8B loads = this group's 4 rows ----
        const ull* pp = (const ull*)pin + repoff + 2 * tid;
        ull v0 = __hip_atomic_load(&pp[0], __ATOMIC_RELAXED, __HIP_MEMORY_SCOPE_AGENT);
        ull v1 = __hip_atomic_load(&pp[1], __ATOMIC_RELAXED, __HIP_MEMORY_SCOPE_AGENT);
        while (((v0 ^ tg2) | (v1 ^ tg2)) & M2) {
            __builtin_amdgcn_s_sleep(1);
            v0 = __hip_atomic_load(&pp[0], __ATOMIC_RELAXED, __HIP_MEMORY_SCOPE_AGENT);
            v1 = __hip_atomic_load(&pp[1], __ATOMIC_RELAXED, __HIP_MEMORY_SCOPE_AGENT);
        }
        float hr0 = __uint_as_float((unsigned)v0         & ~TAGM);
        float hr1 = __uint_as_float((unsigned)(v0 >> 32) & ~TAGM);
        float hr2 = __uint_as_float((unsigned)v1         & ~TAGM);
        float hr3 = __uint_as_float((unsigned)(v1 >> 32) & ~TAGM);

        // threads 2*blk, 2*blk+1 polled this block's own 8 columns
        if ((tid >> 1) == blk) {
            float* hs = &sHold[(tid & 1) * 4];
            hs[0] = hr0; hs[1] = hr1; hs[2] = hr2; hs[3] = hr3;
        }

        // ---- 32 intra-group swizzle broadcasts + 96 FMAs (no barrier) ----
        float a0 = 0.f, a1 = 0.f, a2 = 0.f;
#define GRP(G) { \
        float h0 = bcast8<G>(hr0), h1 = bcast8<G>(hr1); \
        float h2 = bcast8<G>(hr2), h3 = bcast8<G>(hr3); \
        a0 = fmaf(h0, wr[4*G+0], a0); a1 = fmaf(h0, wz[4*G+0], a1); a2 = fmaf(h0, wn[4*G+0], a2); \
        a0 = fmaf(h1, wr[4*G+1], a0); a1 = fmaf(h1, wz[4*G+1], a1); a2 = fmaf(h1, wn[4*G+1], a2); \
        a0 = fmaf(h2, wr[4*G+2], a0); a1 = fmaf(h2, wz[4*G+2], a1); a2 = fmaf(h2, wn[4*G+2], a2); \
        a0 = fmaf(h3, wr[4*G+3], a0); a1 = fmaf(h3, wz[4*G+3], a1); a2 = fmaf(h3, wn[4*G+3], a2); }
        GRP(0) GRP(1) GRP(2) GRP(3) GRP(4) GRP(5) GRP(6) GRP(7)
#undef GRP

        // ---- reduce over the 8 groups of this wave ----
#pragma unroll
        for (int m = 8; m < 64; m <<= 1) {
            a0 += __shfl_xor(a0, m, 64);
            a1 += __shfl_xor(a1, m, 64);
            a2 += __shfl_xor(a2, m, 64);
        }
        if (lane < 8) {
            atomicAdd(&sAcc[0][lane], a0);
            atomicAdd(&sAcc[1][lane], a1);
            atomicAdd(&sAcc[2][lane], a2);
        }
        __syncthreads();                          // BAR2: all adds landed

        // ---- wave0: 3-read finalize + replicated publish + re-init ----
        if (wv == 0) {
            float hnew = 0.f; unsigned pk = 0;
            if (lane < 8) {
                float Sr = sAcc[0][lane];         // aR + Whr.h
                float Sz = sAcc[1][lane];         // aZ + Whz.h
                float Sn = sAcc[2][lane];         // bhn + Whn.h
                float hold = sHold[lane];
                float rg = sigmoid_f(Sr), zg = sigmoid_f(Sz);
                float ng = tanh_f(aN + rg * Sn);
                hnew = (1.f - zg) * ng + zg * hold;
                pk = ((__float_as_uint(hnew) + 512u) & ~TAGM)
                   | ((unsigned)(t + 1) & TAGM);
            }
            if (t == TSTEPS - 1) {
                if (lane < 8) out[col] = hnew;
            } else {
                unsigned c0  = (lane & 3) * 2;
                unsigned pkA = __shfl(pk, (int)c0,     64);
                unsigned pkB = __shfl(pk, (int)c0 + 1, 64);
                ull pkk = (ull)pkA | ((ull)pkB << 32);
                ull* dst = (ull*)pout + (ull)(lane >> 2) * (RSTRIDE / 2)
                         + (ull)blk * 4 + (ull)(lane & 3);
                __hip_atomic_store(dst, pkk, __ATOMIC_RELAXED, __HIP_MEMORY_SCOPE_AGENT);
                if (lane < 8) {   // re-init cells for t+1 (after publish)
                    float xn = sX[t + 1];
                    sAcc[0][lane] = fmaf(xn, vrc, crc);
                    sAcc[1][lane] = fmaf(xn, vzc, czc);
                    aN            = fmaf(xn, vnc, cnc);
                    sAcc[2][lane] = bhc;
                }
            }
        }
        __syncthreads();   // BAR3: publish + re-init before anyone polls t+1
    }
}

extern "C" void kernel_launch(void* const* d_in, const int* in_sizes, int n_in,
                              void* d_out, int out_size, void* d_ws, size_t ws_size,
                              hipStream_t stream) {
    const float* x    = (const float*)d_in[0];
    const float* We   = (const float*)d_in[1];
    const float* be   = (const float*)d_in[2];
    const float* Wir  = (const float*)d_in[3];
    const float* bir  = (const float*)d_in[4];
    const float* Wiz  = (const float*)d_in[5];
    const float* biz  = (const float*)d_in[6];
    const float* Win  = (const float*)d_in[7];
    const float* bin_ = (const float*)d_in[8];
    const float* Whr  = (const float*)d_in[9];
    const float* Whz  = (const float*)d_in[10];
    const float* Whn  = (const float*)d_in[11];
    const float* bhn  = (const float*)d_in[12];

    unsigned* u0 = (unsigned*)d_ws;             // even parity: 16 replicas
    unsigned* u1 = u0 + NREP * RSTRIDE;         // odd parity:  16 replicas
    // total workspace use: 2 * 16 * 2112 * 4B = 270 KB

    gru_all<<<NBLK, NTHR, 0, stream>>>(x, We, be, Wir, bir, Wiz, biz, Win, bin_,
                                       Whr, Whz, Whn, bhn,
                                       (float*)d_out, u0, u1);
}

// Round 7
// 2336.034 us; speedup vs baseline: 1.0564x; 1.0564x over previous
//
#include <hip/hip_runtime.h>

#define HDIM 2048
#define TSTEPS 1024
#define NBLK 256
#define NTHR 512
#define CPB 8
#define TAGM 0x3FFu
#define NREP 8
#define RSTRIDE 2112u   // u32 per replica = 8KB + 256B (channel decorrelation)
#define SPIN_CAP (1 << 21)   // watchdog: ~1s, never reached in normal runs

typedef unsigned long long ull;

__device__ __forceinline__ int snake_src(int t) {
    int y = t >> 5, p = t & 31;
    return (y & 1) ? (y * 32 + 31 - p) : t;
}
__device__ __forceinline__ float sigmoid_f(float v) {
    return __builtin_amdgcn_rcpf(1.f + __expf(-v));
}
__device__ __forceinline__ float tanh_f(float v) {
    return 1.f - 2.f * __builtin_amdgcn_rcpf(__expf(2.f * v) + 1.f);
}
// broadcast from lane ((lane & 0x38) | G): and_mask=0x18 keeps bits 3,4,
// OR in G (0..7); bit 5 (the 32-lane half) is implicitly preserved.
template<int G>
__device__ __forceinline__ float bcast8(float v) {
    return __uint_as_float((unsigned)__builtin_amdgcn_ds_swizzle(
        (int)__float_as_uint(v), (G << 5) | 0x18));
}

// ---------------------------------------------------------------------------
// R7 = R5 (R4 in-block structure + R3-exact publish) + poll watchdog.
// R5/R6 both died at container ACQUISITION (no timing block in the bench
// JSON, unlike every round that actually ran) — infra, not kernel. The
// watchdog is pure insurance: if a protocol hang ever occurs, threads give
// up after ~2M spin iterations and the kernel terminates with garbage
// (clean FAIL + absmax diagnostics) instead of wedging the container.
// Normal waits are ~1e3 cycles; the cap is never hit -> zero perf effect.
// Ledger:
//   L1 (R1): never scatter the publish — one coalesced wave0 store.
//   L2 (R2): publish before anyone spins on the next step (BAR3); no
//            dependent-shuffle chains on the hop path.
//   L3 (R3): 8x replica spread + s_sleep backoff cuts slot contention.
//   L4 (R4): do NOT widen the publish (16 reps/dwordx2 regressed).
// In-block (R4): ds_swizzle group broadcast (no stage, no BAR1); ds_add
// finalize into pre-seeded sAcc; sHold via the 2 threads that poll this
// block's own columns; 2 barriers/step.
// ---------------------------------------------------------------------------
__global__ __launch_bounds__(NTHR, 1) void gru_all(
    const float* __restrict__ x,
    const float* __restrict__ We,  const float* __restrict__ be,
    const float* __restrict__ Wir, const float* __restrict__ bir,
    const float* __restrict__ Wiz, const float* __restrict__ biz,
    const float* __restrict__ Win, const float* __restrict__ bin_,
    const float* __restrict__ Whr, const float* __restrict__ Whz,
    const float* __restrict__ Whn, const float* __restrict__ bhn,
    float* __restrict__ out, unsigned* __restrict__ u0, unsigned* __restrict__ u1)
{
    const int tid  = threadIdx.x;
    const int blk  = blockIdx.x;
    const int c    = tid & 7;
    const int r    = tid >> 3;            // 0..63
    const int col  = blk * CPB + c;
    const int row0 = r * 32;
    const int lane = tid & 63, wv = tid >> 6;

    __shared__ float red[8][6][8];        // init-phase cross-wave reduce
    __shared__ float sX[TSTEPS];          // x in snake order
    __shared__ float sAcc[3][8];          // per-step gate accumulators
    __shared__ float sHold[8];            // h_t for this block's 8 cols

    // ---- one-time: x (snake order) into LDS ----
    for (int i = tid; i < TSTEPS; i += NTHR) sX[i] = x[snake_src(i)];

    // ---- recurrent weights into registers (one-time) ----
    float wr[32], wz[32], wn[32];
#pragma unroll
    for (int k = 0; k < 32; ++k) {
        size_t off = (size_t)(row0 + k) * HDIM + col;
        wr[k] = Whr[off];
        wz[k] = Whz[off];
        wn[k] = Whn[off];
    }

    // ---- rank-1 input-path constants (We/be direct from global) ----
    float eR=0,eZ=0,eN=0,bRa=0,bZa=0,bNa=0;
#pragma unroll 8
    for (int k = 0; k < 32; ++k) {
        int row = row0 + k;
        size_t off = (size_t)row * HDIM + col;
        float we = We[row], bb = be[row];
        float w0 = Wir[off], w1 = Wiz[off], w2 = Win[off];
        eR  = fmaf(we, w0, eR);  bRa = fmaf(bb, w0, bRa);
        eZ  = fmaf(we, w1, eZ);  bZa = fmaf(bb, w1, bZa);
        eN  = fmaf(we, w2, eN);  bNa = fmaf(bb, w2, bNa);
    }
#pragma unroll
    for (int m = 8; m < 64; m <<= 1) {
        eR  += __shfl_xor(eR,  m, 64); eZ  += __shfl_xor(eZ,  m, 64);
        eN  += __shfl_xor(eN,  m, 64); bRa += __shfl_xor(bRa, m, 64);
        bZa += __shfl_xor(bZa, m, 64); bNa += __shfl_xor(bNa, m, 64);
    }
    if (lane < 8) {
        red[wv][0][lane]=eR;  red[wv][1][lane]=eZ;  red[wv][2][lane]=eN;
        red[wv][3][lane]=bRa; red[wv][4][lane]=bZa; red[wv][5][lane]=bNa;
    }
    __syncthreads();   // red + sX staged

    float vrc=0,vzc=0,vnc=0,crc=0,czc=0,cnc=0,bhc=0;
    float aN=0;
    unsigned pk1 = 0;
    if (tid < 8) {
#pragma unroll
        for (int w = 0; w < 8; ++w) {
            vrc += red[w][0][tid]; vzc += red[w][1][tid]; vnc += red[w][2][tid];
            crc += red[w][3][tid]; czc += red[w][4][tid]; cnc += red[w][5][tid];
        }
        crc += bir[col]; czc += biz[col]; cnc += bin_[col];
        bhc = bhn[col];

        // ---- step 0: h_0 == 0, fully local; h_1 with tag 1 ----
        float x0 = sX[0];
        float ar = fmaf(x0, vrc, crc);
        float az = fmaf(x0, vzc, czc);
        float an = fmaf(x0, vnc, cnc);
        float rg = sigmoid_f(ar), zg = sigmoid_f(az);
        float ng = tanh_f(fmaf(rg, bhc, an));
        float h1 = (1.f - zg) * ng;
        pk1 = ((__float_as_uint(h1) + 512u) & ~TAGM) | 1u;

        // precompute t=1 input terms; initialize the t=1 accumulator cells
        float x1 = sX[1];
        sAcc[0][tid] = fmaf(x1, vrc, crc);
        sAcc[1][tid] = fmaf(x1, vzc, czc);
        aN           = fmaf(x1, vnc, cnc);
        sAcc[2][tid] = bhc;
    }
    // replicated step-0 publish: one dword per wave0 lane (R3-exact shape)
    if (wv == 0) {
        unsigned pkb = __shfl(pk1, lane & 7, 64);
        __hip_atomic_store(&u1[(unsigned)(lane >> 3) * RSTRIDE + (unsigned)blk * 8u + (unsigned)(lane & 7)],
                           pkb, __ATOMIC_RELAXED, __HIP_MEMORY_SCOPE_AGENT);
    }
    __syncthreads();   // sAcc init + publish issued before anyone polls t=1

    const ull  M2     = 0x000003FF000003FFull;
    const ull  repoff = (ull)(blk & 7) * (RSTRIDE / 2);   // ull units
    int alive = 1;     // watchdog flag: once 0, never poll again

    for (int t = 1; t < TSTEPS; ++t) {
        const unsigned* pin  = (t & 1) ? u1 : u0;
        unsigned*       pout = (t & 1) ? u0 : u1;
        const unsigned  tg   = (unsigned)t & TAGM;
        const ull       tg2  = ((ull)tg << 32) | (ull)tg;

        // ---- poll assigned replica: 2x8B loads = this group's 4 rows ----
        const ull* pp = (const ull*)pin + repoff + 2 * tid;
        ull v0 = __hip_atomic_load(&pp[0], __ATOMIC_RELAXED, __HIP_MEMORY_SCOPE_AGENT);
        ull v1 = __hip_atomic_load(&pp[1], __ATOMIC_RELAXED, __HIP_MEMORY_SCOPE_AGENT);
        if (alive) {
            int guard = 0;
            while (((v0 ^ tg2) | (v1 ^ tg2)) & M2) {
                __builtin_amdgcn_s_sleep(1);
                v0 = __hip_atomic_load(&pp[0], __ATOMIC_RELAXED, __HIP_MEMORY_SCOPE_AGENT);
                v1 = __hip_atomic_load(&pp[1], __ATOMIC_RELAXED, __HIP_MEMORY_SCOPE_AGENT);
                if (++guard > SPIN_CAP) { alive = 0; break; }  // give up, fail clean
            }
        }
        float hr0 = __uint_as_float((unsigned)v0         & ~TAGM);
        float hr1 = __uint_as_float((unsigned)(v0 >> 32) & ~TAGM);
        float hr2 = __uint_as_float((unsigned)v1         & ~TAGM);
        float hr3 = __uint_as_float((unsigned)(v1 >> 32) & ~TAGM);

        // threads 2*blk, 2*blk+1 polled this block's own 8 columns
        if ((tid >> 1) == blk) {
            float* hs = &sHold[(tid & 1) * 4];
            hs[0] = hr0; hs[1] = hr1; hs[2] = hr2; hs[3] = hr3;
        }

        // ---- 32 intra-group swizzle broadcasts + 96 FMAs (no barrier) ----
        float a0 = 0.f, a1 = 0.f, a2 = 0.f;
#define GRP(G) { \
        float h0 = bcast8<G>(hr0), h1 = bcast8<G>(hr1); \
        float h2 = bcast8<G>(hr2), h3 = bcast8<G>(hr3); \
        a0 = fmaf(h0, wr[4*G+0], a0); a1 = fmaf(h0, wz[4*G+0], a1); a2 = fmaf(h0, wn[4*G+0], a2); \
        a0 = fmaf(h1, wr[4*G+1], a0); a1 = fmaf(h1, wz[4*G+1], a1); a2 = fmaf(h1, wn[4*G+1], a2); \
        a0 = fmaf(h2, wr[4*G+2], a0); a1 = fmaf(h2, wz[4*G+2], a1); a2 = fmaf(h2, wn[4*G+2], a2); \
        a0 = fmaf(h3, wr[4*G+3], a0); a1 = fmaf(h3, wz[4*G+3], a1); a2 = fmaf(h3, wn[4*G+3], a2); }
        GRP(0) GRP(1) GRP(2) GRP(3) GRP(4) GRP(5) GRP(6) GRP(7)
#undef GRP

        // ---- reduce over the 8 groups of this wave ----
#pragma unroll
        for (int m = 8; m < 64; m <<= 1) {
            a0 += __shfl_xor(a0, m, 64);
            a1 += __shfl_xor(a1, m, 64);
            a2 += __shfl_xor(a2, m, 64);
        }
        if (lane < 8) {
            atomicAdd(&sAcc[0][lane], a0);
            atomicAdd(&sAcc[1][lane], a1);
            atomicAdd(&sAcc[2][lane], a2);
        }
        __syncthreads();                          // BAR2: all adds landed

        // ---- wave0: 3-read finalize + R3-shape publish + re-init ----
        if (wv == 0) {
            float hnew = 0.f; unsigned pk = 0;
            if (lane < 8) {
                float Sr = sAcc[0][lane];         // aR + Whr.h
                float Sz = sAcc[1][lane];         // aZ + Whz.h
                float Sn = sAcc[2][lane];         // bhn + Whn.h
                float hold = sHold[lane];
                float rg = sigmoid_f(Sr), zg = sigmoid_f(Sz);
                float ng = tanh_f(aN + rg * Sn);
                hnew = (1.f - zg) * ng + zg * hold;
                pk = ((__float_as_uint(hnew) + 512u) & ~TAGM)
                   | ((unsigned)(t + 1) & TAGM);
            }
            if (t == TSTEPS - 1) {
                if (lane < 8) out[col] = hnew;
            } else {
                unsigned pkb = __shfl(pk, lane & 7, 64);
                __hip_atomic_store(&pout[(unsigned)(lane >> 3) * RSTRIDE + (unsigned)blk * 8u + (unsigned)(lane & 7)],
                                   pkb, __ATOMIC_RELAXED, __HIP_MEMORY_SCOPE_AGENT);
                if (lane < 8) {   // re-init cells for t+1 (after publish)
                    float xn = sX[t + 1];
                    sAcc[0][lane] = fmaf(xn, vrc, crc);
                    sAcc[1][lane] = fmaf(xn, vzc, czc);
                    aN            = fmaf(xn, vnc, cnc);
                    sAcc[2][lane] = bhc;
                }
            }
        }
        __syncthreads();   // BAR3: publish + re-init before anyone polls t+1
    }
}

extern "C" void kernel_launch(void* const* d_in, const int* in_sizes, int n_in,
                              void* d_out, int out_size, void* d_ws, size_t ws_size,
                              hipStream_t stream) {
    const float* x    = (const float*)d_in[0];
    const float* We   = (const float*)d_in[1];
    const float* be   = (const float*)d_in[2];
    const float* Wir  = (const float*)d_in[3];
    const float* bir  = (const float*)d_in[4];
    const float* Wiz  = (const float*)d_in[5];
    const float* biz  = (const float*)d_in[6];
    const float* Win  = (const float*)d_in[7];
    const float* bin_ = (const float*)d_in[8];
    const float* Whr  = (const float*)d_in[9];
    const float* Whz  = (const float*)d_in[10];
    const float* Whn  = (const float*)d_in[11];
    const float* bhn  = (const float*)d_in[12];

    unsigned* u0 = (unsigned*)d_ws;             // even parity: 8 replicas
    unsigned* u1 = u0 + NREP * RSTRIDE;         // odd parity:  8 replicas
    // total workspace use: 2 * 8 * 2112 * 4B = 132 KB

    gru_all<<<NBLK, NTHR, 0, stream>>>(x, We, be, Wir, bir, Wiz, biz, Win, bin_,
                                       Whr, Whz, Whn, bhn,
                                       (float*)d_out, u0, u1);
}

// Round 8
// 2273.450 us; speedup vs baseline: 1.0855x; 1.0275x over previous
//
#include <hip/hip_runtime.h>

#define HDIM 2048
#define TSTEPS 1024
#define NBLK 256
#define NTHR 512
#define CPB 8
#define TAGM 0x3FFu
#define NREP 8
#define RSTRIDE 2112u   // u32 per replica = 8KB + 256B (channel decorrelation)
#define SPIN_CAP (1 << 21)   // watchdog: ~1s, never reached in normal runs

typedef unsigned long long ull;

__device__ __forceinline__ int snake_src(int t) {
    int y = t >> 5, p = t & 31;
    return (y & 1) ? (y * 32 + 31 - p) : t;
}
__device__ __forceinline__ float sigmoid_f(float v) {
    return __builtin_amdgcn_rcpf(1.f + __expf(-v));
}
__device__ __forceinline__ float tanh_f(float v) {
    return 1.f - 2.f * __builtin_amdgcn_rcpf(__expf(2.f * v) + 1.f);
}
// broadcast from lane ((lane & 0x38) | G): and_mask=0x18 keeps bits 3,4,
// OR in G (0..7); bit 5 (the 32-lane half) is implicitly preserved.
template<int G>
__device__ __forceinline__ float bcast8(float v) {
    return __uint_as_float((unsigned)__builtin_amdgcn_ds_swizzle(
        (int)__float_as_uint(v), (G << 5) | 0x18));
}

// raw barrier: drain LDS only; global (vmem) loads/stores stay in flight.
// All intra-block data exchanged across these barriers is LDS (sAcc, sNext),
// so lgkmcnt(0) is the exact required fence; leaving vmcnt outstanding is
// what lets the t+1 tag prefetch overlap finalize+publish.
#define BAR_RAW() do { asm volatile("s_waitcnt lgkmcnt(0)" ::: "memory"); \
                       __builtin_amdgcn_s_barrier(); } while (0)

// ---------------------------------------------------------------------------
// R8 = R7 + two hop attacks (the hop is ~3800 of ~5300 cyc/step; slot region
// is L3-resident — FETCH shows polls never reach HBM):
//   1. SELF-BYPASS: wave0's finalize writes hnew into LDS sNext[8]; the 2
//      threads polling this block's OWN columns read sNext instead of L3.
//      Deletes a guaranteed store->L3->load round-trip from every block's
//      critical path (those 2 threads were the per-block stragglers).
//      sNext also supplies `hold` (read before overwrite, same lane).
//   2. TAG PREFETCH across raw barriers: next-step poll loads issue right
//      after the atomicAdds; BAR2/BAR3 become {lgkmcnt(0); s_barrier} so
//      the loads stay in flight across finalize+publish (~600-1000 cyc).
//      Loop top checks prefetched values; stale -> original spin+watchdog.
//      Torn 8B reads across two 4B publishes are benign (tag check covers
//      both halves; retry reloads).
// Ledger: L1 coalesced wave0 publish; L2 publish issued before next-step
// spinning (still between BAR2/BAR3); L3 8-replica spread + s_sleep;
// L4 8 replicas / dword-per-lane exactly.
// ---------------------------------------------------------------------------
__global__ __launch_bounds__(NTHR, 1) void gru_all(
    const float* __restrict__ x,
    const float* __restrict__ We,  const float* __restrict__ be,
    const float* __restrict__ Wir, const float* __restrict__ bir,
    const float* __restrict__ Wiz, const float* __restrict__ biz,
    const float* __restrict__ Win, const float* __restrict__ bin_,
    const float* __restrict__ Whr, const float* __restrict__ Whz,
    const float* __restrict__ Whn, const float* __restrict__ bhn,
    float* __restrict__ out, unsigned* __restrict__ u0, unsigned* __restrict__ u1)
{
    const int tid  = threadIdx.x;
    const int blk  = blockIdx.x;
    const int c    = tid & 7;
    const int r    = tid >> 3;            // 0..63
    const int col  = blk * CPB + c;
    const int row0 = r * 32;
    const int lane = tid & 63, wv = tid >> 6;

    __shared__ float red[8][6][8];        // init-phase cross-wave reduce
    __shared__ float sX[TSTEPS];          // x in snake order
    __shared__ float sAcc[3][8];          // per-step gate accumulators
    __shared__ float sNext[8];            // own 8 cols of h_{t} (full precision)

    // ---- one-time: x (snake order) into LDS ----
    for (int i = tid; i < TSTEPS; i += NTHR) sX[i] = x[snake_src(i)];

    // ---- recurrent weights into registers (one-time) ----
    float wr[32], wz[32], wn[32];
#pragma unroll
    for (int k = 0; k < 32; ++k) {
        size_t off = (size_t)(row0 + k) * HDIM + col;
        wr[k] = Whr[off];
        wz[k] = Whz[off];
        wn[k] = Whn[off];
    }

    // ---- rank-1 input-path constants (We/be direct from global) ----
    float eR=0,eZ=0,eN=0,bRa=0,bZa=0,bNa=0;
#pragma unroll 8
    for (int k = 0; k < 32; ++k) {
        int row = row0 + k;
        size_t off = (size_t)row * HDIM + col;
        float we = We[row], bb = be[row];
        float w0 = Wir[off], w1 = Wiz[off], w2 = Win[off];
        eR  = fmaf(we, w0, eR);  bRa = fmaf(bb, w0, bRa);
        eZ  = fmaf(we, w1, eZ);  bZa = fmaf(bb, w1, bZa);
        eN  = fmaf(we, w2, eN);  bNa = fmaf(bb, w2, bNa);
    }
#pragma unroll
    for (int m = 8; m < 64; m <<= 1) {
        eR  += __shfl_xor(eR,  m, 64); eZ  += __shfl_xor(eZ,  m, 64);
        eN  += __shfl_xor(eN,  m, 64); bRa += __shfl_xor(bRa, m, 64);
        bZa += __shfl_xor(bZa, m, 64); bNa += __shfl_xor(bNa, m, 64);
    }
    if (lane < 8) {
        red[wv][0][lane]=eR;  red[wv][1][lane]=eZ;  red[wv][2][lane]=eN;
        red[wv][3][lane]=bRa; red[wv][4][lane]=bZa; red[wv][5][lane]=bNa;
    }
    __syncthreads();   // red + sX staged

    float vrc=0,vzc=0,vnc=0,crc=0,czc=0,cnc=0,bhc=0;
    float aN=0;
    unsigned pk1 = 0;
    if (tid < 8) {
#pragma unroll
        for (int w = 0; w < 8; ++w) {
            vrc += red[w][0][tid]; vzc += red[w][1][tid]; vnc += red[w][2][tid];
            crc += red[w][3][tid]; czc += red[w][4][tid]; cnc += red[w][5][tid];
        }
        crc += bir[col]; czc += biz[col]; cnc += bin_[col];
        bhc = bhn[col];

        // ---- step 0: h_0 == 0, fully local; h_1 with tag 1 ----
        float x0 = sX[0];
        float ar = fmaf(x0, vrc, crc);
        float az = fmaf(x0, vzc, czc);
        float an = fmaf(x0, vnc, cnc);
        float rg = sigmoid_f(ar), zg = sigmoid_f(az);
        float ng = tanh_f(fmaf(rg, bhc, an));
        float h1 = (1.f - zg) * ng;
        pk1 = ((__float_as_uint(h1) + 512u) & ~TAGM) | 1u;
        sNext[tid] = h1;                  // self-bypass seed for t=1

        // precompute t=1 input terms; initialize the t=1 accumulator cells
        float x1 = sX[1];
        sAcc[0][tid] = fmaf(x1, vrc, crc);
        sAcc[1][tid] = fmaf(x1, vzc, czc);
        aN           = fmaf(x1, vnc, cnc);
        sAcc[2][tid] = bhc;
    }
    // replicated step-0 publish: one dword per wave0 lane (R3-exact shape)
    if (wv == 0) {
        unsigned pkb = __shfl(pk1, lane & 7, 64);
        __hip_atomic_store(&u1[(unsigned)(lane >> 3) * RSTRIDE + (unsigned)blk * 8u + (unsigned)(lane & 7)],
                           pkb, __ATOMIC_RELAXED, __HIP_MEMORY_SCOPE_AGENT);
    }
    __syncthreads();   // sNext/sAcc init + publish issued before anyone polls

    const ull  M2     = 0x000003FF000003FFull;
    const ull  repoff = (ull)(blk & 7) * (RSTRIDE / 2);   // ull units
    const bool selfcol = ((tid >> 1) == blk);             // polls own 8 cols
    int alive = 1;     // watchdog flag: once 0, never poll again

    // ---- initial prefetch for t=1 ----
    ull v0p, v1p;
    {
        const ull* pp1 = (const ull*)u1 + repoff + 2 * tid;
        v0p = __hip_atomic_load(&pp1[0], __ATOMIC_RELAXED, __HIP_MEMORY_SCOPE_AGENT);
        v1p = __hip_atomic_load(&pp1[1], __ATOMIC_RELAXED, __HIP_MEMORY_SCOPE_AGENT);
    }

    for (int t = 1; t < TSTEPS; ++t) {
        const unsigned* pin  = (t & 1) ? u1 : u0;
        unsigned*       pout = (t & 1) ? u0 : u1;
        const unsigned  tg   = (unsigned)t & TAGM;
        const ull       tg2  = ((ull)tg << 32) | (ull)tg;

        float hr0, hr1, hr2, hr3;
        if (selfcol) {
            // own columns: values live in LDS, skip the L3 round-trip
            const float* sn = &sNext[(tid & 1) * 4];
            hr0 = sn[0]; hr1 = sn[1]; hr2 = sn[2]; hr3 = sn[3];
        } else {
            ull v0 = v0p, v1 = v1p;
            if ((((v0 ^ tg2) | (v1 ^ tg2)) & M2) && alive) {
                const ull* pp = (const ull*)pin + repoff + 2 * tid;
                int guard = 0;
                do {
                    __builtin_amdgcn_s_sleep(1);
                    v0 = __hip_atomic_load(&pp[0], __ATOMIC_RELAXED, __HIP_MEMORY_SCOPE_AGENT);
                    v1 = __hip_atomic_load(&pp[1], __ATOMIC_RELAXED, __HIP_MEMORY_SCOPE_AGENT);
                    if (++guard > SPIN_CAP) { alive = 0; break; }
                } while (((v0 ^ tg2) | (v1 ^ tg2)) & M2);
            }
            hr0 = __uint_as_float((unsigned)v0         & ~TAGM);
            hr1 = __uint_as_float((unsigned)(v0 >> 32) & ~TAGM);
            hr2 = __uint_as_float((unsigned)v1         & ~TAGM);
            hr3 = __uint_as_float((unsigned)(v1 >> 32) & ~TAGM);
        }

        // ---- 32 intra-group swizzle broadcasts + 96 FMAs (no barrier) ----
        float a0 = 0.f, a1 = 0.f, a2 = 0.f;
#define GRP(G) { \
        float h0 = bcast8<G>(hr0), h1 = bcast8<G>(hr1); \
        float h2 = bcast8<G>(hr2), h3 = bcast8<G>(hr3); \
        a0 = fmaf(h0, wr[4*G+0], a0); a1 = fmaf(h0, wz[4*G+0], a1); a2 = fmaf(h0, wn[4*G+0], a2); \
        a0 = fmaf(h1, wr[4*G+1], a0); a1 = fmaf(h1, wz[4*G+1], a1); a2 = fmaf(h1, wn[4*G+1], a2); \
        a0 = fmaf(h2, wr[4*G+2], a0); a1 = fmaf(h2, wz[4*G+2], a1); a2 = fmaf(h2, wn[4*G+2], a2); \
        a0 = fmaf(h3, wr[4*G+3], a0); a1 = fmaf(h3, wz[4*G+3], a1); a2 = fmaf(h3, wn[4*G+3], a2); }
        GRP(0) GRP(1) GRP(2) GRP(3) GRP(4) GRP(5) GRP(6) GRP(7)
#undef GRP

        // ---- reduce over the 8 groups of this wave ----
#pragma unroll
        for (int m = 8; m < 64; m <<= 1) {
            a0 += __shfl_xor(a0, m, 64);
            a1 += __shfl_xor(a1, m, 64);
            a2 += __shfl_xor(a2, m, 64);
        }
        if (lane < 8) {
            atomicAdd(&sAcc[0][lane], a0);
            atomicAdd(&sAcc[1][lane], a1);
            atomicAdd(&sAcc[2][lane], a2);
        }

        // ---- prefetch t+1 slots; stays in flight across both barriers ----
        {
            const ull* ppn = (const ull*)pout + repoff + 2 * tid;
            v0p = __hip_atomic_load(&ppn[0], __ATOMIC_RELAXED, __HIP_MEMORY_SCOPE_AGENT);
            v1p = __hip_atomic_load(&ppn[1], __ATOMIC_RELAXED, __HIP_MEMORY_SCOPE_AGENT);
        }
        BAR_RAW();                                // BAR2: LDS adds landed

        // ---- wave0: 3-read finalize + publish + sNext + re-init ----
        if (wv == 0) {
            float hnew = 0.f; unsigned pk = 0;
            if (lane < 8) {
                float Sr = sAcc[0][lane];         // aR + Whr.h
                float Sz = sAcc[1][lane];         // aZ + Whz.h
                float Sn = sAcc[2][lane];         // bhn + Whn.h
                float hold = sNext[lane];         // own h_t, full precision
                float rg = sigmoid_f(Sr), zg = sigmoid_f(Sz);
                float ng = tanh_f(aN + rg * Sn);
                hnew = (1.f - zg) * ng + zg * hold;
                pk = ((__float_as_uint(hnew) + 512u) & ~TAGM)
                   | ((unsigned)(t + 1) & TAGM);
            }
            if (t == TSTEPS - 1) {
                if (lane < 8) out[col] = hnew;
            } else {
                unsigned pkb = __shfl(pk, lane & 7, 64);
                __hip_atomic_store(&pout[(unsigned)(lane >> 3) * RSTRIDE + (unsigned)blk * 8u + (unsigned)(lane & 7)],
                                   pkb, __ATOMIC_RELAXED, __HIP_MEMORY_SCOPE_AGENT);
                if (lane < 8) {   // self-bypass + re-init for t+1
                    sNext[lane] = hnew;
                    float xn = sX[t + 1];
                    sAcc[0][lane] = fmaf(xn, vrc, crc);
                    sAcc[1][lane] = fmaf(xn, vzc, czc);
                    aN            = fmaf(xn, vnc, cnc);
                    sAcc[2][lane] = bhc;
                }
            }
        }
        BAR_RAW();   // BAR3: publish issued + LDS state ready; vmem in flight
    }
}

extern "C" void kernel_launch(void* const* d_in, const int* in_sizes, int n_in,
                              void* d_out, int out_size, void* d_ws, size_t ws_size,
                              hipStream_t stream) {
    const float* x    = (const float*)d_in[0];
    const float* We   = (const float*)d_in[1];
    const float* be   = (const float*)d_in[2];
    const float* Wir  = (const float*)d_in[3];
    const float* bir  = (const float*)d_in[4];
    const float* Wiz  = (const float*)d_in[5];
    const float* biz  = (const float*)d_in[6];
    const float* Win  = (const float*)d_in[7];
    const float* bin_ = (const float*)d_in[8];
    const float* Whr  = (const float*)d_in[9];
    const float* Whz  = (const float*)d_in[10];
    const float* Whn  = (const float*)d_in[11];
    const float* bhn  = (const float*)d_in[12];

    unsigned* u0 = (unsigned*)d_ws;             // even parity: 8 replicas
    unsigned* u1 = u0 + NREP * RSTRIDE;         // odd parity:  8 replicas
    // total workspace use: 2 * 8 * 2112 * 4B = 132 KB

    gru_all<<<NBLK, NTHR, 0, stream>>>(x, We, be, Wir, bir, Wiz, biz, Win, bin_,
                                       Whr, Whz, Whn, bhn,
                                       (float*)d_out, u0, u1);
}

// Round 9
// 2225.505 us; speedup vs baseline: 1.1089x; 1.0215x over previous
//
#include <hip/hip_runtime.h>

#define HDIM 2048
#define TSTEPS 1024
#define NBLK 256
#define NTHR 512
#define CPB 8
#define TAGM 0x3FFu
#define NREP 8
#define RSTRIDE 2112u   // u32 per replica = 8KB + 256B (channel decorrelation)
#define SPIN_CAP (1 << 21)   // watchdog: ~1s, never reached in normal runs

typedef unsigned long long ull;

__device__ __forceinline__ int snake_src(int t) {
    int y = t >> 5, p = t & 31;
    return (y & 1) ? (y * 32 + 31 - p) : t;
}
__device__ __forceinline__ float sigmoid_f(float v) {
    return __builtin_amdgcn_rcpf(1.f + __expf(-v));
}
__device__ __forceinline__ float tanh_f(float v) {
    return 1.f - 2.f * __builtin_amdgcn_rcpf(__expf(2.f * v) + 1.f);
}
// broadcast from lane ((lane & 0x38) | G): and_mask=0x18 keeps bits 3,4,
// OR in G (0..7); bit 5 (the 32-lane half) is implicitly preserved.
template<int G>
__device__ __forceinline__ float bcast8(float v) {
    return __uint_as_float((unsigned)__builtin_amdgcn_ds_swizzle(
        (int)__float_as_uint(v), (G << 5) | 0x18));
}

// raw barrier: drain LDS only; vmem (tag prefetch) stays in flight.
#define BAR_RAW() do { asm volatile("s_waitcnt lgkmcnt(0)" ::: "memory"); \
                       __builtin_amdgcn_s_barrier(); } while (0)

// ---------------------------------------------------------------------------
// R9 = R8 + LAST-FINISHER FINALIZE (publish the moment the data exists):
//   - each wave, after its sAcc atomicAdds, bumps an LDS counter; the wave
//     observing old==7 runs finalize+publish IMMEDIATELY. LDS ops from a
//     wave complete in order, so counter==7 implies all adds landed; the
//     finalizer's subsequent reads are issued after observation -> safe.
//   - removes the {BAR2 -> wave0 wake -> finalize} round from the publish
//     path (~300-450 cyc/step); finalizer is a hot, just-ran wave.
//   - ONE raw barrier per step (after finalize): guarantees publish issued
//     + sAcc/sAN/sNext re-init done before any thread proceeds (ledger L2).
//   - per-column constants (v*,c*,bh) moved to LDS so ANY wave can
//     finalize/re-init; aN is now LDS sAN[8].
//   - spin: on stale prefetch, one immediate reload BEFORE first s_sleep
//     (prefetch is usually stale-by-timing; catches publishes that landed
//     during our FMA phase without the 64-cyc sleep tax).
// Carried: self-bypass sNext (R8), tag prefetch across raw barriers (R8),
// ds_swizzle broadcast + ds_add finalize (R4/R7), R3-exact publish shape
// (L1/L4), 8-replica spread + sleep backoff (L3), watchdog (R7).
// ---------------------------------------------------------------------------
__global__ __launch_bounds__(NTHR, 1) void gru_all(
    const float* __restrict__ x,
    const float* __restrict__ We,  const float* __restrict__ be,
    const float* __restrict__ Wir, const float* __restrict__ bir,
    const float* __restrict__ Wiz, const float* __restrict__ biz,
    const float* __restrict__ Win, const float* __restrict__ bin_,
    const float* __restrict__ Whr, const float* __restrict__ Whz,
    const float* __restrict__ Whn, const float* __restrict__ bhn,
    float* __restrict__ out, unsigned* __restrict__ u0, unsigned* __restrict__ u1)
{
    const int tid  = threadIdx.x;
    const int blk  = blockIdx.x;
    const int c    = tid & 7;
    const int r    = tid >> 3;            // 0..63
    const int col  = blk * CPB + c;
    const int row0 = r * 32;
    const int lane = tid & 63, wv = tid >> 6;

    __shared__ float red[8][6][8];        // init-phase cross-wave reduce
    __shared__ float sX[TSTEPS];          // x in snake order
    __shared__ float sAcc[3][8];          // per-step gate accumulators
    __shared__ float sNext[8];            // own 8 cols of h_t (full precision)
    __shared__ float sAN[8];              // input-path n-term for current t
    __shared__ float sVr[8], sVz[8], sVn[8];   // rank-1 row-sums (const)
    __shared__ float sCr[8], sCz[8], sCn[8];   // bias-path consts
    __shared__ float sBh[8];                   // bhn consts
    __shared__ unsigned sCnt;             // waves-done counter

    // ---- one-time: x (snake order) into LDS ----
    for (int i = tid; i < TSTEPS; i += NTHR) sX[i] = x[snake_src(i)];
    if (tid == 0) sCnt = 0u;

    // ---- recurrent weights into registers (one-time) ----
    float wr[32], wz[32], wn[32];
#pragma unroll
    for (int k = 0; k < 32; ++k) {
        size_t off = (size_t)(row0 + k) * HDIM + col;
        wr[k] = Whr[off];
        wz[k] = Whz[off];
        wn[k] = Whn[off];
    }

    // ---- rank-1 input-path constants (We/be direct from global) ----
    float eR=0,eZ=0,eN=0,bRa=0,bZa=0,bNa=0;
#pragma unroll 8
    for (int k = 0; k < 32; ++k) {
        int row = row0 + k;
        size_t off = (size_t)row * HDIM + col;
        float we = We[row], bb = be[row];
        float w0 = Wir[off], w1 = Wiz[off], w2 = Win[off];
        eR  = fmaf(we, w0, eR);  bRa = fmaf(bb, w0, bRa);
        eZ  = fmaf(we, w1, eZ);  bZa = fmaf(bb, w1, bZa);
        eN  = fmaf(we, w2, eN);  bNa = fmaf(bb, w2, bNa);
    }
#pragma unroll
    for (int m = 8; m < 64; m <<= 1) {
        eR  += __shfl_xor(eR,  m, 64); eZ  += __shfl_xor(eZ,  m, 64);
        eN  += __shfl_xor(eN,  m, 64); bRa += __shfl_xor(bRa, m, 64);
        bZa += __shfl_xor(bZa, m, 64); bNa += __shfl_xor(bNa, m, 64);
    }
    if (lane < 8) {
        red[wv][0][lane]=eR;  red[wv][1][lane]=eZ;  red[wv][2][lane]=eN;
        red[wv][3][lane]=bRa; red[wv][4][lane]=bZa; red[wv][5][lane]=bNa;
    }
    __syncthreads();   // red + sX staged

    unsigned pk1 = 0;
    if (tid < 8) {
        float vrc=0,vzc=0,vnc=0,crc=0,czc=0,cnc=0;
#pragma unroll
        for (int w = 0; w < 8; ++w) {
            vrc += red[w][0][tid]; vzc += red[w][1][tid]; vnc += red[w][2][tid];
            crc += red[w][3][tid]; czc += red[w][4][tid]; cnc += red[w][5][tid];
        }
        crc += bir[col]; czc += biz[col]; cnc += bin_[col];
        float bhc = bhn[col];

        // constants -> LDS so ANY wave can finalize/re-init
        sVr[tid]=vrc; sVz[tid]=vzc; sVn[tid]=vnc;
        sCr[tid]=crc; sCz[tid]=czc; sCn[tid]=cnc; sBh[tid]=bhc;

        // ---- step 0: h_0 == 0, fully local; h_1 with tag 1 ----
        float x0 = sX[0];
        float ar = fmaf(x0, vrc, crc);
        float az = fmaf(x0, vzc, czc);
        float an = fmaf(x0, vnc, cnc);
        float rg = sigmoid_f(ar), zg = sigmoid_f(az);
        float ng = tanh_f(fmaf(rg, bhc, an));
        float h1 = (1.f - zg) * ng;
        pk1 = ((__float_as_uint(h1) + 512u) & ~TAGM) | 1u;
        sNext[tid] = h1;                  // self-bypass seed for t=1

        // seed t=1 accumulators + n-term
        float x1 = sX[1];
        sAcc[0][tid] = fmaf(x1, vrc, crc);
        sAcc[1][tid] = fmaf(x1, vzc, czc);
        sAN[tid]     = fmaf(x1, vnc, cnc);
        sAcc[2][tid] = bhc;
    }
    // replicated step-0 publish: one dword per wave0 lane (R3-exact shape)
    if (wv == 0) {
        unsigned pkb = __shfl(pk1, lane & 7, 64);
        __hip_atomic_store(&u1[(unsigned)(lane >> 3) * RSTRIDE + (unsigned)blk * 8u + (unsigned)(lane & 7)],
                           pkb, __ATOMIC_RELAXED, __HIP_MEMORY_SCOPE_AGENT);
    }
    __syncthreads();   // LDS state + publish issued before anyone polls

    const ull  M2     = 0x000003FF000003FFull;
    const ull  repoff = (ull)(blk & 7) * (RSTRIDE / 2);   // ull units
    const bool selfcol = ((tid >> 1) == blk);             // polls own 8 cols
    int alive = 1;     // watchdog flag: once 0, never poll again

    // ---- initial prefetch for t=1 ----
    ull v0p, v1p;
    {
        const ull* pp1 = (const ull*)u1 + repoff + 2 * tid;
        v0p = __hip_atomic_load(&pp1[0], __ATOMIC_RELAXED, __HIP_MEMORY_SCOPE_AGENT);
        v1p = __hip_atomic_load(&pp1[1], __ATOMIC_RELAXED, __HIP_MEMORY_SCOPE_AGENT);
    }

    for (int t = 1; t < TSTEPS; ++t) {
        const unsigned* pin  = (t & 1) ? u1 : u0;
        unsigned*       pout = (t & 1) ? u0 : u1;
        const unsigned  tg   = (unsigned)t & TAGM;
        const ull       tg2  = ((ull)tg << 32) | (ull)tg;

        float hr0, hr1, hr2, hr3;
        if (selfcol) {
            // own columns: values live in LDS, skip the L3 round-trip
            const float* sn = &sNext[(tid & 1) * 4];
            hr0 = sn[0]; hr1 = sn[1]; hr2 = sn[2]; hr3 = sn[3];
        } else {
            ull v0 = v0p, v1 = v1p;
            if (((v0 ^ tg2) | (v1 ^ tg2)) & M2) {
                const ull* pp = (const ull*)pin + repoff + 2 * tid;
                // immediate reload (no sleep): prefetch is usually stale-by-
                // timing; a publish may have landed during our FMA phase.
                v0 = __hip_atomic_load(&pp[0], __ATOMIC_RELAXED, __HIP_MEMORY_SCOPE_AGENT);
                v1 = __hip_atomic_load(&pp[1], __ATOMIC_RELAXED, __HIP_MEMORY_SCOPE_AGENT);
                if ((((v0 ^ tg2) | (v1 ^ tg2)) & M2) && alive) {
                    int guard = 0;
                    do {
                        __builtin_amdgcn_s_sleep(1);
                        v0 = __hip_atomic_load(&pp[0], __ATOMIC_RELAXED, __HIP_MEMORY_SCOPE_AGENT);
                        v1 = __hip_atomic_load(&pp[1], __ATOMIC_RELAXED, __HIP_MEMORY_SCOPE_AGENT);
                        if (++guard > SPIN_CAP) { alive = 0; break; }
                    } while (((v0 ^ tg2) | (v1 ^ tg2)) & M2);
                }
            }
            hr0 = __uint_as_float((unsigned)v0         & ~TAGM);
            hr1 = __uint_as_float((unsigned)(v0 >> 32) & ~TAGM);
            hr2 = __uint_as_float((unsigned)v1         & ~TAGM);
            hr3 = __uint_as_float((unsigned)(v1 >> 32) & ~TAGM);
        }

        // ---- 32 intra-group swizzle broadcasts + 96 FMAs (no barrier) ----
        float a0 = 0.f, a1 = 0.f, a2 = 0.f;
#define GRP(G) { \
        float h0 = bcast8<G>(hr0), h1 = bcast8<G>(hr1); \
        float h2 = bcast8<G>(hr2), h3 = bcast8<G>(hr3); \
        a0 = fmaf(h0, wr[4*G+0], a0); a1 = fmaf(h0, wz[4*G+0], a1); a2 = fmaf(h0, wn[4*G+0], a2); \
        a0 = fmaf(h1, wr[4*G+1], a0); a1 = fmaf(h1, wz[4*G+1], a1); a2 = fmaf(h1, wn[4*G+1], a2); \
        a0 = fmaf(h2, wr[4*G+2], a0); a1 = fmaf(h2, wz[4*G+2], a1); a2 = fmaf(h2, wn[4*G+2], a2); \
        a0 = fmaf(h3, wr[4*G+3], a0); a1 = fmaf(h3, wz[4*G+3], a1); a2 = fmaf(h3, wn[4*G+3], a2); }
        GRP(0) GRP(1) GRP(2) GRP(3) GRP(4) GRP(5) GRP(6) GRP(7)
#undef GRP

        // ---- reduce over the 8 groups of this wave ----
#pragma unroll
        for (int m = 8; m < 64; m <<= 1) {
            a0 += __shfl_xor(a0, m, 64);
            a1 += __shfl_xor(a1, m, 64);
            a2 += __shfl_xor(a2, m, 64);
        }
        if (lane < 8) {
            atomicAdd(&sAcc[0][lane], a0);
            atomicAdd(&sAcc[1][lane], a1);
            atomicAdd(&sAcc[2][lane], a2);
        }

        // ---- prefetch t+1 slots; stays in flight across the barrier ----
        {
            const ull* ppn = (const ull*)pout + repoff + 2 * tid;
            v0p = __hip_atomic_load(&ppn[0], __ATOMIC_RELAXED, __HIP_MEMORY_SCOPE_AGENT);
            v1p = __hip_atomic_load(&ppn[1], __ATOMIC_RELAXED, __HIP_MEMORY_SCOPE_AGENT);
        }

        // ---- last-finisher election: wave seeing old==7 finalizes NOW ----
        unsigned oldv = 0;
        if (lane == 0) oldv = atomicAdd(&sCnt, 1u);
        oldv = __builtin_amdgcn_readfirstlane(oldv);
        if (oldv == 7u) {
            float hnew = 0.f; unsigned pk = 0;
            if (lane < 8) {
                float Sr = sAcc[0][lane];         // aR + Whr.h
                float Sz = sAcc[1][lane];         // aZ + Whz.h
                float Sn = sAcc[2][lane];         // bhn + Whn.h
                float hold = sNext[lane];         // own h_t, full precision
                float rg = sigmoid_f(Sr), zg = sigmoid_f(Sz);
                float ng = tanh_f(sAN[lane] + rg * Sn);
                hnew = (1.f - zg) * ng + zg * hold;
                pk = ((__float_as_uint(hnew) + 512u) & ~TAGM)
                   | ((unsigned)(t + 1) & TAGM);
            }
            if (t == TSTEPS - 1) {
                if (lane < 8) out[col] = hnew;
            } else {
                unsigned pkb = __shfl(pk, lane & 7, 64);
                __hip_atomic_store(&pout[(unsigned)(lane >> 3) * RSTRIDE + (unsigned)blk * 8u + (unsigned)(lane & 7)],
                                   pkb, __ATOMIC_RELAXED, __HIP_MEMORY_SCOPE_AGENT);
                if (lane < 8) {   // self-bypass + re-init for t+1
                    sNext[lane] = hnew;
                    float xn = sX[t + 1];
                    sAcc[0][lane] = fmaf(xn, sVr[lane], sCr[lane]);
                    sAcc[1][lane] = fmaf(xn, sVz[lane], sCz[lane]);
                    sAN[lane]     = fmaf(xn, sVn[lane], sCn[lane]);
                    sAcc[2][lane] = sBh[lane];
                }
                if (lane == 0) sCnt = 0u;
            }
        }
        // single barrier: publish issued + LDS re-init done before anyone
        // proceeds to t+1 (ledger L2); vmem prefetch stays in flight.
        BAR_RAW();
    }
}

extern "C" void kernel_launch(void* const* d_in, const int* in_sizes, int n_in,
                              void* d_out, int out_size, void* d_ws, size_t ws_size,
                              hipStream_t stream) {
    const float* x    = (const float*)d_in[0];
    const float* We   = (const float*)d_in[1];
    const float* be   = (const float*)d_in[2];
    const float* Wir  = (const float*)d_in[3];
    const float* bir  = (const float*)d_in[4];
    const float* Wiz  = (const float*)d_in[5];
    const float* biz  = (const float*)d_in[6];
    const float* Win  = (const float*)d_in[7];
    const float* bin_ = (const float*)d_in[8];
    const float* Whr  = (const float*)d_in[9];
    const float* Whz  = (const float*)d_in[10];
    const float* Whn  = (const float*)d_in[11];
    const float* bhn  = (const float*)d_in[12];

    unsigned* u0 = (unsigned*)d_ws;             // even parity: 8 replicas
    unsigned* u1 = u0 + NREP * RSTRIDE;         // odd parity:  8 replicas
    // total workspace use: 2 * 8 * 2112 * 4B = 132 KB

    gru_all<<<NBLK, NTHR, 0, stream>>>(x, We, be, Wir, bir, Wiz, biz, Win, bin_,
                                       Whr, Whz, Whn, bhn,
                                       (float*)d_out, u0, u1);
}